// Round 17
// baseline (185.022 us; speedup 1.0000x reference)
//
#include <hip/hip_runtime.h>

#define DD 128

using bf16 = __bf16;
typedef __bf16 bf16x8 __attribute__((ext_vector_type(8)));
typedef float f32x4 __attribute__((ext_vector_type(4)));
typedef float f32x2 __attribute__((ext_vector_type(2)));

__device__ inline bf16x8 cvt8(const float* p) {
  f32x4 v0 = *(const f32x4*)p;
  f32x4 v1 = *(const f32x4*)(p + 4);
  bf16x8 r;
  r[0] = (bf16)v0[0]; r[1] = (bf16)v0[1]; r[2] = (bf16)v0[2]; r[3] = (bf16)v0[3];
  r[4] = (bf16)v1[0]; r[5] = (bf16)v1[1]; r[6] = (bf16)v1[2]; r[7] = (bf16)v1[3];
  return r;
}

// pack 8 f32 -> 8 fp8 e4m3 (uint2)
__device__ inline uint2 pk8fp8(const float* f) {
  int u0 = __builtin_amdgcn_cvt_pk_fp8_f32(f[0], f[1], 0, 0);
  u0 = __builtin_amdgcn_cvt_pk_fp8_f32(f[2], f[3], u0, 1);
  int u1 = __builtin_amdgcn_cvt_pk_fp8_f32(f[4], f[5], 0, 0);
  u1 = __builtin_amdgcn_cvt_pk_fp8_f32(f[6], f[7], u1, 1);
  uint2 r; r.x = (unsigned)u0; r.y = (unsigned)u1; return r;
}

// fast tanh: 1 - 2/(e^{2x}+1); v_exp + v_rcp, saturates correctly at +-1
__device__ inline float ftanh(float x) {
  float e2 = __expf(2.0f * x);
  return 1.0f - 2.0f * __builtin_amdgcn_rcpf(e2 + 1.0f);
}

// XOR swizzle for [128 rows][256 B] LDS tiles (G4)
__device__ inline int swz(int o) { return o ^ (((o >> 8) & 7) << 4); }

// ---- fused prologue: zero cnt | weights->bf16 | x->bf16+fp8 --------------
__global__ void k_prep(int* __restrict__ cnt, int N,
                       const float* __restrict__ w0, const float* __restrict__ w1,
                       const float* __restrict__ w2, const float* __restrict__ w3,
                       const float* __restrict__ w4, bf16* __restrict__ wb, int totalW,
                       const float* __restrict__ x, bf16* __restrict__ xb,
                       unsigned char* __restrict__ xb8, int total8,
                       int nbZ, int nbW) {
  int b = blockIdx.x;
  if (b < nbZ) {
    int i = b * 256 + threadIdx.x;
    if (i < N) cnt[i] = 0;
  } else if (b < nbZ + nbW) {
    int i = (b - nbZ) * 256 + threadIdx.x;
    if (i < totalW) {
      int m = i >> 14;           // DD*DD = 16384
      int r = i & 16383;
      const float* s = m == 0 ? w0 : m == 1 ? w1 : m == 2 ? w2 : m == 3 ? w3 : w4;
      wb[i] = (bf16)s[r];
    }
  } else {
    int i = (b - nbZ - nbW) * 256 + threadIdx.x;
    if (i < total8) {
      float f[8];
      f32x4 v0 = *(const f32x4*)(x + (size_t)i * 8);
      f32x4 v1 = *(const f32x4*)(x + (size_t)i * 8 + 4);
#pragma unroll
      for (int j = 0; j < 4; ++j) { f[j] = v0[j]; f[4 + j] = v1[j]; }
      bf16x8 r;
#pragma unroll
      for (int j = 0; j < 8; ++j) r[j] = (bf16)f[j];
      *(bf16x8*)(xb + (size_t)i * 8) = r;
      *(uint2*)(xb8 + (size_t)i * 8) = pk8fp8(f);
    }
  }
}

// ---- h1 bf16 -> fp8 copy (for layer-2 gather) ---------------------------
__global__ void k_cvt8(const bf16* __restrict__ h, unsigned char* __restrict__ h8,
                       int total8) {
  int i = blockIdx.x * 256 + threadIdx.x;
  if (i >= total8) return;
  bf16x8 v = *(const bf16x8*)(h + (size_t)i * 8);
  float f[8];
#pragma unroll
  for (int j = 0; j < 8; ++j) f[j] = (float)v[j];
  *(uint2*)(h8 + (size_t)i * 8) = pk8fp8(f);
}

// ---- CSR build ----------------------------------------------------------
__global__ void k_hist(const int* __restrict__ dst, int* __restrict__ cnt, int E) {
  int e = blockIdx.x * 256 + threadIdx.x;
  if (e < E) atomicAdd(&cnt[dst[e]], 1);
}

__global__ __launch_bounds__(256) void k_scan1(const int* __restrict__ cnt,
                                               int* __restrict__ bsum, int N) {
  __shared__ int sm[256];
  int t = threadIdx.x;
  int i = blockIdx.x * 256 + t;
  sm[t] = (i < N) ? cnt[i] : 0;
  __syncthreads();
#pragma unroll
  for (int d = 128; d > 0; d >>= 1) {
    if (t < d) sm[t] += sm[t + d];
    __syncthreads();
  }
  if (t == 0) bsum[blockIdx.x] = sm[0];
}

__global__ __launch_bounds__(256) void k_scan2(int* __restrict__ bsum, int nb) {
  __shared__ int sm[256];
  int t = threadIdx.x;
  int v = (t < nb) ? bsum[t] : 0;
  sm[t] = v;
  __syncthreads();
#pragma unroll
  for (int d = 1; d < 256; d <<= 1) {
    int u = (t >= d) ? sm[t - d] : 0;
    __syncthreads();
    sm[t] += u;
    __syncthreads();
  }
  if (t < nb) bsum[t] = sm[t] - v;   // exclusive prefix
}

__global__ __launch_bounds__(256) void k_scan3(const int* __restrict__ cnt,
                                               const int* __restrict__ bsum,
                                               int* __restrict__ offs,
                                               int* __restrict__ cursor, int N) {
  __shared__ int sm[256];
  int t = threadIdx.x;
  int i = blockIdx.x * 256 + t;
  int v = (i < N) ? cnt[i] : 0;
  sm[t] = v;
  __syncthreads();
#pragma unroll
  for (int d = 1; d < 256; d <<= 1) {
    int u = (t >= d) ? sm[t - d] : 0;
    __syncthreads();
    sm[t] += u;
    __syncthreads();
  }
  int incl = sm[t];
  int base = bsum[blockIdx.x];
  if (i < N) {
    int ex = base + incl - v;
    offs[i] = ex;
    cursor[i] = ex;
    if (i == N - 1) offs[N] = base + incl;
  }
}

__global__ void k_scatter(const int* __restrict__ src, const int* __restrict__ dst,
                          int* __restrict__ cursor, int* __restrict__ ssrc, int E) {
  int e = blockIdx.x * 256 + threadIdx.x;
  if (e < E) {
    int d = dst[e];
    int p = atomicAdd(&cursor[d], 1);
    ssrc[p] = src[e];
  }
}

// ---- fused SAGE layer: aggregate (fp8 gather) + GEMM --------------------
// Block = 1024 threads (16 waves), Ws+Wn staged in 64 KB swizzled LDS.
// Grid = 256 blocks; tile = wv*gridDim + blockIdx (CU-spread).
// Neighbor rows are gathered in fp8 e4m3 (Hb8, half the L2-fill bytes of
// bf16 — the gather is an L2-fill BW floor, 8 XCDs x working set);
// unpacked with v_cvt_pk_f32_fp8 into f32 accumulators. Self fragments,
// residual, and GEMM stay bf16.
// MODE 0: H1out = (bf16)v
// MODE 1: Resb = (bf16)(Xres + h1 + 0.5*v)
template <int MODE>
__global__ __launch_bounds__(1024, 1) void k_layer(const bf16* __restrict__ Hb,
                                                   const unsigned char* __restrict__ Hb8,
                                                   const int* __restrict__ offs,
                                                   const int* __restrict__ ssrc,
                                                   const bf16* __restrict__ Wsb,
                                                   const bf16* __restrict__ Wnb,
                                                   const float* __restrict__ bias,
                                                   const float* __restrict__ Xres,
                                                   bf16* __restrict__ H1out,
                                                   bf16* __restrict__ Resb, int N) {
  __shared__ char smem[65536];   // [2][128 rows][256 B], swizzled
  int t = threadIdx.x;
#pragma unroll
  for (int m = 0; m < 2; ++m) {
    const bf16* wsrc = m ? Wnb : Wsb;
#pragma unroll
    for (int it = 0; it < 2; ++it) {
      int o = (it * 1024 + t) * 16;         // linear byte offset in matrix
      *(bf16x8*)(smem + m * 32768 + swz(o)) = *(const bf16x8*)(wsrc + o / 2);
    }
  }
  __syncthreads();

  int wv = t >> 6;
  int lane = t & 63;
  int tile = wv * gridDim.x + blockIdx.x;   // CU-spread tile mapping
  int n0 = tile << 4;
  if (n0 >= N) return;
  int lr = lane & 15;
  int g = lane >> 4;
  int lk = g << 3;                          // k offset in elems (8-elem chunk)

  int node = n0 + lr;

  // A1 (self) fragments (bf16)
  const bf16* a1p = Hb + (size_t)node * DD + lk;
  bf16x8 a1[4];
#pragma unroll
  for (int kk = 0; kk < 4; ++kk) a1[kk] = *(const bf16x8*)(a1p + kk * 32);

  // aggregate neighbor mean into A2 fragments: fp8 rows, f32 accumulate
  int beg = offs[node], end = offs[node + 1];
  float acc[4][8];
#pragma unroll
  for (int kk = 0; kk < 4; ++kk)
#pragma unroll
    for (int j = 0; j < 8; ++j) acc[kk][j] = 0.f;
  for (int i = beg; i < end; ++i) {
    int s = ssrc[i];
    const unsigned char* hp = Hb8 + (size_t)s * DD + lk;  // fp8: 1 B/elem
#pragma unroll
    for (int kk = 0; kk < 4; ++kk) {
      uint2 v = *(const uint2*)(hp + kk * 32);
      f32x2 p;
      p = __builtin_amdgcn_cvt_pk_f32_fp8(v.x, 0); acc[kk][0] += p.x; acc[kk][1] += p.y;
      p = __builtin_amdgcn_cvt_pk_f32_fp8(v.x, 1); acc[kk][2] += p.x; acc[kk][3] += p.y;
      p = __builtin_amdgcn_cvt_pk_f32_fp8(v.y, 0); acc[kk][4] += p.x; acc[kk][5] += p.y;
      p = __builtin_amdgcn_cvt_pk_f32_fp8(v.y, 1); acc[kk][6] += p.x; acc[kk][7] += p.y;
    }
  }
  float inv = (end > beg) ? 1.0f / (float)(end - beg) : 0.f;
  bf16x8 a2[4];
#pragma unroll
  for (int kk = 0; kk < 4; ++kk)
#pragma unroll
    for (int j = 0; j < 8; ++j) a2[kk][j] = (bf16)(acc[kk][j] * inv);

  int rb = n0 + (g << 2);
#pragma unroll
  for (int j = 0; j < 8; ++j) {
    int row = j * 16 + lr;
    int rbase = row * 256 + lk * 2;         // byte offset of this lane's chunk
    f32x4 cs = {0.f, 0.f, 0.f, 0.f};
    f32x4 cn = {0.f, 0.f, 0.f, 0.f};
#pragma unroll
    for (int kk = 0; kk < 4; ++kk) {
      int ro = swz(rbase + kk * 64);
      bf16x8 bs = *(const bf16x8*)(smem + ro);
      bf16x8 bn = *(const bf16x8*)(smem + 32768 + ro);
      cs = __builtin_amdgcn_mfma_f32_16x16x32_bf16(a1[kk], bs, cs, 0, 0, 0);
      cn = __builtin_amdgcn_mfma_f32_16x16x32_bf16(a2[kk], bn, cn, 0, 0, 0);
    }
    int col = j * 16 + lr;
    float bb = bias[col];
#pragma unroll
    for (int r = 0; r < 4; ++r) {
      size_t idx = (size_t)(rb + r) * DD + col;
      float v = cs[r] + cn[r] + bb;
      if (MODE == 0) H1out[idx] = (bf16)v;
      else           Resb[idx] = (bf16)(Xres[idx] + (float)Hb[idx] + 0.5f * v);
    }
  }
}

// ---- fused attention scores, LDS-staged W_attn --------------------------
__global__ __launch_bounds__(512, 4) void k_attn2(const bf16* __restrict__ resb,
                                                  const float* __restrict__ v2f,
                                                  const bf16* __restrict__ Wab,
                                                  const float* __restrict__ bias,
                                                  const float* __restrict__ att,
                                                  float* __restrict__ partial,
                                                  int nbA, int N) {
  __shared__ char smem[32768];   // [128 rows][256 B], swizzled
  __shared__ float smr[8];
  int t = threadIdx.x;
#pragma unroll
  for (int it = 0; it < 4; ++it) {
    int o = (it * 512 + t) * 16;            // linear byte offset in matrix
    *(bf16x8*)(smem + swz(o)) = *(const bf16x8*)(Wab + o / 2);
  }
  __syncthreads();

  int wv = t >> 6;
  int lane = t & 63;
  int gwid = blockIdx.x * 8 + wv;
  int view = gwid & 1;
  int tile = gwid >> 1;
  int n0 = tile << 4;
  float part = 0.f;
  if (n0 < N) {
    int lr = lane & 15;
    int lk = (lane >> 4) << 3;
    bf16x8 a[4];
    if (view) {
      const float* ap = v2f + (size_t)(n0 + lr) * DD + lk;
#pragma unroll
      for (int kk = 0; kk < 4; ++kk) a[kk] = cvt8(ap + kk * 32);
    } else {
      const bf16* ap = resb + (size_t)(n0 + lr) * DD + lk;
#pragma unroll
      for (int kk = 0; kk < 4; ++kk) a[kk] = *(const bf16x8*)(ap + kk * 32);
    }
#pragma unroll
    for (int j = 0; j < 8; ++j) {
      int row = j * 16 + lr;
      int rbase = row * 256 + lk * 2;
      f32x4 c = {0.f, 0.f, 0.f, 0.f};
#pragma unroll
      for (int kk = 0; kk < 4; ++kk) {
        bf16x8 bw = *(const bf16x8*)(smem + swz(rbase + kk * 64));
        c = __builtin_amdgcn_mfma_f32_16x16x32_bf16(a[kk], bw, c, 0, 0, 0);
      }
      int col = j * 16 + lr;
      float aw = att[col], bb = bias[col];
#pragma unroll
      for (int r = 0; r < 4; ++r) part += aw * ftanh(c[r] + bb);
    }
  }
#pragma unroll
  for (int d = 1; d < 64; d <<= 1) part += __shfl_xor(part, d);
  if (lane == 0) smr[wv] = part;
  __syncthreads();
  if (t == 0) {
    partial[blockIdx.x]       = smr[0] + smr[2] + smr[4] + smr[6];  // view 0
    partial[nbA + blockIdx.x] = smr[1] + smr[3] + smr[5] + smr[7];  // view 1
  }
}

// ---- reduce partials -> scores[2] ---------------------------------------
__global__ __launch_bounds__(256) void k_score(const float* __restrict__ partial,
                                               float* __restrict__ scores, int nbA) {
  __shared__ float sm[256];
  int t = threadIdx.x;
#pragma unroll
  for (int v = 0; v < 2; ++v) {
    float s = 0.f;
    for (int i = t; i < nbA; i += 256) s += partial[v * nbA + i];
    sm[t] = s;
    __syncthreads();
#pragma unroll
    for (int d = 128; d > 0; d >>= 1) {
      if (t < d) sm[t] += sm[t + d];
      __syncthreads();
    }
    if (t == 0) scores[v] = sm[0];
    __syncthreads();
  }
}

// ---- final blend: out = b0*res(bf16) + b1*view2(f32) --------------------
__global__ void k_fin(float* __restrict__ out, const bf16* __restrict__ resb,
                      const float* __restrict__ v2,
                      const float* __restrict__ scores, float invN, int total8) {
  int i = blockIdx.x * 256 + threadIdx.x;
  if (i >= total8) return;
  float s0 = scores[0] * invN, s1 = scores[1] * invN;
  float m = fmaxf(s0, s1);
  float e0 = expf(s0 - m), e1 = expf(s1 - m);
  float inv = 1.0f / (e0 + e1);
  float b0 = e0 * inv, b1 = e1 * inv;
  bf16x8 r = ((const bf16x8*)resb)[i];
  f32x4 w0 = ((const f32x4*)v2)[2 * i];
  f32x4 w1 = ((const f32x4*)v2)[2 * i + 1];
  f32x4 o0, o1;
#pragma unroll
  for (int j = 0; j < 4; ++j) {
    o0[j] = b0 * (float)r[j] + b1 * w0[j];
    o1[j] = b0 * (float)r[4 + j] + b1 * w1[j];
  }
  ((f32x4*)out)[2 * i] = o0;
  ((f32x4*)out)[2 * i + 1] = o1;
}

extern "C" void kernel_launch(void* const* d_in, const int* in_sizes, int n_in,
                              void* d_out, int out_size, void* d_ws, size_t ws_size,
                              hipStream_t stream) {
  const float* x   = (const float*)d_in[0];
  const float* v2  = (const float*)d_in[1];
  const float* Wn1 = (const float*)d_in[2];
  const float* Ws1 = (const float*)d_in[3];
  const float* b1  = (const float*)d_in[4];
  const float* Wn2 = (const float*)d_in[5];
  const float* Ws2 = (const float*)d_in[6];
  const float* b2  = (const float*)d_in[7];
  const float* Wa  = (const float*)d_in[8];
  const float* ba  = (const float*)d_in[9];
  const float* att = (const float*)d_in[10];
  const int*  src  = (const int*)d_in[11];
  const int*  dst  = (const int*)d_in[12];
  const int D = in_sizes[4];        // 128
  const int N = in_sizes[0] / D;    // 50000
  const int E = in_sizes[11];       // 640000
  float* out = (float*)d_out;

  char* ws = (char*)d_ws;
  size_t o = 0;
  auto alloc = [&](size_t bytes) -> void* {
    void* p = ws + o;
    o += (bytes + 255) & ~(size_t)255;
    return p;
  };
  int*  cnt    = (int*)alloc((size_t)N * 4);
  int*  offs   = (int*)alloc((size_t)(N + 1) * 4);
  int*  cursor = (int*)alloc((size_t)N * 4);
  int*  ssrc   = (int*)alloc((size_t)E * 4);
  bf16* xb     = (bf16*)alloc((size_t)N * D * 2);
  bf16* h1b    = (bf16*)alloc((size_t)N * D * 2);
  bf16* resb   = (bf16*)alloc((size_t)N * D * 2);
  unsigned char* xb8  = (unsigned char*)alloc((size_t)N * D);
  unsigned char* h1b8 = (unsigned char*)alloc((size_t)N * D);
  bf16* wb     = (bf16*)alloc((size_t)5 * D * D * 2);
  float* sc    = (float*)alloc(2 * 4);
  int nb = (N + 255) / 256;
  int*  bsum   = (int*)alloc((size_t)nb * 4);

  int tilesPerView = (N + 15) / 16;          // 3125
  int attnWaves = 2 * tilesPerView;          // 6250
  int nbA = (attnWaves + 7) / 8;             // 782 blocks (8 waves each)
  float* apart = (float*)alloc((size_t)2 * nbA * 4);

  // fused prologue
  int nbZ = (N + 255) / 256;                 // zero cnt
  int nbW = (5 * D * D + 255) / 256;         // weights -> bf16
  int nbX = (N * D / 8 + 255) / 256;         // x -> bf16 + fp8
  k_prep<<<nbZ + nbW + nbX, 256, 0, stream>>>(cnt, N, Ws1, Wn1, Ws2, Wn2, Wa, wb,
                                              5 * D * D, x, xb, xb8, N * D / 8,
                                              nbZ, nbW);

  k_hist<<<(E + 255) / 256, 256, 0, stream>>>(dst, cnt, E);
  k_scan1<<<nb, 256, 0, stream>>>(cnt, bsum, N);
  k_scan2<<<1, 256, 0, stream>>>(bsum, nb);
  k_scan3<<<nb, 256, 0, stream>>>(cnt, bsum, offs, cursor, N);
  k_scatter<<<(E + 255) / 256, 256, 0, stream>>>(src, dst, cursor, ssrc, E);

  int layerBlocks = 256;                     // 1 block/CU; waves CU-spread

  // layer 1: h1 (bf16) = x@Ws1^T + mean_nb(x,fp8)@Wn1^T + b1
  k_layer<0><<<layerBlocks, 1024, 0, stream>>>(xb, xb8, offs, ssrc, wb, wb + D * D,
                                               b1, nullptr, h1b, nullptr, N);
  // h1 -> fp8 for layer-2 gather
  k_cvt8<<<(N * D / 8 + 255) / 256, 256, 0, stream>>>(h1b, h1b8, N * D / 8);
  // layer 2: res (bf16) = x + h1 + 0.5*h2
  k_layer<1><<<layerBlocks, 1024, 0, stream>>>(h1b, h1b8, offs, ssrc, wb + 2 * D * D,
                                               wb + 3 * D * D, b2, x, nullptr, resb, N);
  // fused attention scores over [res, view2], W_attn LDS-staged
  k_attn2<<<nbA, 512, 0, stream>>>(resb, v2, wb + 4 * D * D, ba, att, apart, nbA, N);
  k_score<<<1, 256, 0, stream>>>(apart, sc, nbA);
  // final blend
  k_fin<<<((N * D / 8) + 255) / 256, 256, 0, stream>>>(out, resb, v2, sc,
                                                       1.0f / (float)N, N * D / 8);
}

// Round 18
// 170.536 us; speedup vs baseline: 1.0849x; 1.0849x over previous
//
#include <hip/hip_runtime.h>

#define DD 128

using bf16 = __bf16;
typedef __bf16 bf16x8 __attribute__((ext_vector_type(8)));
typedef float f32x4 __attribute__((ext_vector_type(4)));
typedef float f32x2 __attribute__((ext_vector_type(2)));

__device__ inline bf16x8 cvt8(const float* p) {
  f32x4 v0 = *(const f32x4*)p;
  f32x4 v1 = *(const f32x4*)(p + 4);
  bf16x8 r;
  r[0] = (bf16)v0[0]; r[1] = (bf16)v0[1]; r[2] = (bf16)v0[2]; r[3] = (bf16)v0[3];
  r[4] = (bf16)v1[0]; r[5] = (bf16)v1[1]; r[6] = (bf16)v1[2]; r[7] = (bf16)v1[3];
  return r;
}

// pack 8 f32 -> 8 fp8 e4m3 (uint2)
__device__ inline uint2 pk8fp8(const float* f) {
  int u0 = __builtin_amdgcn_cvt_pk_fp8_f32(f[0], f[1], 0, 0);
  u0 = __builtin_amdgcn_cvt_pk_fp8_f32(f[2], f[3], u0, 1);
  int u1 = __builtin_amdgcn_cvt_pk_fp8_f32(f[4], f[5], 0, 0);
  u1 = __builtin_amdgcn_cvt_pk_fp8_f32(f[6], f[7], u1, 1);
  uint2 r; r.x = (unsigned)u0; r.y = (unsigned)u1; return r;
}

// unpack one dword (4 fp8) into 4 accumulators
__device__ inline void acc4fp8(unsigned w, float* a) {
  f32x2 p;
  p = __builtin_amdgcn_cvt_pk_f32_fp8(w, 0); a[0] += p.x; a[1] += p.y;
  p = __builtin_amdgcn_cvt_pk_f32_fp8(w, 1); a[2] += p.x; a[3] += p.y;
}

// fast tanh: 1 - 2/(e^{2x}+1); v_exp + v_rcp, saturates correctly at +-1
__device__ inline float ftanh(float x) {
  float e2 = __expf(2.0f * x);
  return 1.0f - 2.0f * __builtin_amdgcn_rcpf(e2 + 1.0f);
}

// XOR swizzle for [128 rows][256 B] LDS tiles (G4)
__device__ inline int swz(int o) { return o ^ (((o >> 8) & 7) << 4); }

// ---- fused prologue: zero cnt | weights->bf16 | x->bf16+fp8 --------------
__global__ void k_prep(int* __restrict__ cnt, int N,
                       const float* __restrict__ w0, const float* __restrict__ w1,
                       const float* __restrict__ w2, const float* __restrict__ w3,
                       const float* __restrict__ w4, bf16* __restrict__ wb, int totalW,
                       const float* __restrict__ x, bf16* __restrict__ xb,
                       unsigned char* __restrict__ xb8, int total8,
                       int nbZ, int nbW) {
  int b = blockIdx.x;
  if (b < nbZ) {
    int i = b * 256 + threadIdx.x;
    if (i < N) cnt[i] = 0;
  } else if (b < nbZ + nbW) {
    int i = (b - nbZ) * 256 + threadIdx.x;
    if (i < totalW) {
      int m = i >> 14;           // DD*DD = 16384
      int r = i & 16383;
      const float* s = m == 0 ? w0 : m == 1 ? w1 : m == 2 ? w2 : m == 3 ? w3 : w4;
      wb[i] = (bf16)s[r];
    }
  } else {
    int i = (b - nbZ - nbW) * 256 + threadIdx.x;
    if (i < total8) {
      float f[8];
      f32x4 v0 = *(const f32x4*)(x + (size_t)i * 8);
      f32x4 v1 = *(const f32x4*)(x + (size_t)i * 8 + 4);
#pragma unroll
      for (int j = 0; j < 4; ++j) { f[j] = v0[j]; f[4 + j] = v1[j]; }
      bf16x8 r;
#pragma unroll
      for (int j = 0; j < 8; ++j) r[j] = (bf16)f[j];
      *(bf16x8*)(xb + (size_t)i * 8) = r;
      *(uint2*)(xb8 + (size_t)i * 8) = pk8fp8(f);
    }
  }
}

// ---- h1 bf16 -> fp8 copy (for layer-2 gather) ---------------------------
__global__ void k_cvt8(const bf16* __restrict__ h, unsigned char* __restrict__ h8,
                       int total8) {
  int i = blockIdx.x * 256 + threadIdx.x;
  if (i >= total8) return;
  bf16x8 v = *(const bf16x8*)(h + (size_t)i * 8);
  float f[8];
#pragma unroll
  for (int j = 0; j < 8; ++j) f[j] = (float)v[j];
  *(uint2*)(h8 + (size_t)i * 8) = pk8fp8(f);
}

// ---- CSR build ----------------------------------------------------------
__global__ void k_hist(const int* __restrict__ dst, int* __restrict__ cnt, int E) {
  int e = blockIdx.x * 256 + threadIdx.x;
  if (e < E) atomicAdd(&cnt[dst[e]], 1);
}

__global__ __launch_bounds__(256) void k_scan1(const int* __restrict__ cnt,
                                               int* __restrict__ bsum, int N) {
  __shared__ int sm[256];
  int t = threadIdx.x;
  int i = blockIdx.x * 256 + t;
  sm[t] = (i < N) ? cnt[i] : 0;
  __syncthreads();
#pragma unroll
  for (int d = 128; d > 0; d >>= 1) {
    if (t < d) sm[t] += sm[t + d];
    __syncthreads();
  }
  if (t == 0) bsum[blockIdx.x] = sm[0];
}

__global__ __launch_bounds__(256) void k_scan2(int* __restrict__ bsum, int nb) {
  __shared__ int sm[256];
  int t = threadIdx.x;
  int v = (t < nb) ? bsum[t] : 0;
  sm[t] = v;
  __syncthreads();
#pragma unroll
  for (int d = 1; d < 256; d <<= 1) {
    int u = (t >= d) ? sm[t - d] : 0;
    __syncthreads();
    sm[t] += u;
    __syncthreads();
  }
  if (t < nb) bsum[t] = sm[t] - v;   // exclusive prefix
}

__global__ __launch_bounds__(256) void k_scan3(const int* __restrict__ cnt,
                                               const int* __restrict__ bsum,
                                               int* __restrict__ offs,
                                               int* __restrict__ cursor, int N) {
  __shared__ int sm[256];
  int t = threadIdx.x;
  int i = blockIdx.x * 256 + t;
  int v = (i < N) ? cnt[i] : 0;
  sm[t] = v;
  __syncthreads();
#pragma unroll
  for (int d = 1; d < 256; d <<= 1) {
    int u = (t >= d) ? sm[t - d] : 0;
    __syncthreads();
    sm[t] += u;
    __syncthreads();
  }
  int incl = sm[t];
  int base = bsum[blockIdx.x];
  if (i < N) {
    int ex = base + incl - v;
    offs[i] = ex;
    cursor[i] = ex;
    if (i == N - 1) offs[N] = base + incl;
  }
}

__global__ void k_scatter(const int* __restrict__ src, const int* __restrict__ dst,
                          int* __restrict__ cursor, int* __restrict__ ssrc, int E) {
  int e = blockIdx.x * 256 + threadIdx.x;
  if (e < E) {
    int d = dst[e];
    int p = atomicAdd(&cursor[d], 1);
    ssrc[p] = src[e];
  }
}

// ---- fused SAGE layer: aggregate (fp8 gather) + GEMM --------------------
// Block = 1024 threads (16 waves), Ws+Wn staged in 64 KB swizzled LDS.
// Grid = 256 blocks; tile = wv*gridDim + blockIdx (CU-spread).
// K-PERMUTED GEMM: the k-sum is order-independent, so lane-group g / MFMA
// step kk carries global k = g*32 + kk*8 + j (A and B agree). This makes
// each lane's per-edge gather footprint CONTIGUOUS 32 fp8 bytes -> 2
// dwordx4 requests/edge instead of 4 strided ones (the gather is bound by
// request-count x latency, not bytes — R16/R17 evidence).
// MODE 0: H1out = (bf16)v
// MODE 1: Resb = (bf16)(Xres + h1 + 0.5*v)
template <int MODE>
__global__ __launch_bounds__(1024, 1) void k_layer(const bf16* __restrict__ Hb,
                                                   const unsigned char* __restrict__ Hb8,
                                                   const int* __restrict__ offs,
                                                   const int* __restrict__ ssrc,
                                                   const bf16* __restrict__ Wsb,
                                                   const bf16* __restrict__ Wnb,
                                                   const float* __restrict__ bias,
                                                   const float* __restrict__ Xres,
                                                   bf16* __restrict__ H1out,
                                                   bf16* __restrict__ Resb, int N) {
  __shared__ char smem[65536];   // [2][128 rows][256 B], swizzled
  int t = threadIdx.x;
#pragma unroll
  for (int m = 0; m < 2; ++m) {
    const bf16* wsrc = m ? Wnb : Wsb;
#pragma unroll
    for (int it = 0; it < 2; ++it) {
      int o = (it * 1024 + t) * 16;         // linear byte offset in matrix
      *(bf16x8*)(smem + m * 32768 + swz(o)) = *(const bf16x8*)(wsrc + o / 2);
    }
  }
  __syncthreads();

  int wv = t >> 6;
  int lane = t & 63;
  int tile = wv * gridDim.x + blockIdx.x;   // CU-spread tile mapping
  int n0 = tile << 4;
  if (n0 >= N) return;
  int lr = lane & 15;
  int g = lane >> 4;

  int node = n0 + lr;

  // A1 (self) fragments, permuted k: a1[kk] = elements g*32 + kk*8 + [0,8)
  const bf16* a1p = Hb + (size_t)node * DD + g * 32;
  bf16x8 a1[4];
#pragma unroll
  for (int kk = 0; kk < 4; ++kk) a1[kk] = *(const bf16x8*)(a1p + kk * 8);

  // aggregate neighbor mean: contiguous 32 fp8 bytes/lane = 2 requests/edge
  int beg = offs[node], end = offs[node + 1];
  float acc[4][8];
#pragma unroll
  for (int kk = 0; kk < 4; ++kk)
#pragma unroll
    for (int j = 0; j < 8; ++j) acc[kk][j] = 0.f;
  for (int i = beg; i < end; ++i) {
    int s = ssrc[i];
    const unsigned char* hp = Hb8 + (size_t)s * DD + g * 32;
    uint4 u0 = *(const uint4*)(hp);         // elements g*32 + [0,16)
    uint4 u1 = *(const uint4*)(hp + 16);    // elements g*32 + [16,32)
    acc4fp8(u0.x, &acc[0][0]); acc4fp8(u0.y, &acc[0][4]);
    acc4fp8(u0.z, &acc[1][0]); acc4fp8(u0.w, &acc[1][4]);
    acc4fp8(u1.x, &acc[2][0]); acc4fp8(u1.y, &acc[2][4]);
    acc4fp8(u1.z, &acc[3][0]); acc4fp8(u1.w, &acc[3][4]);
  }
  float inv = (end > beg) ? 1.0f / (float)(end - beg) : 0.f;
  bf16x8 a2[4];
#pragma unroll
  for (int kk = 0; kk < 4; ++kk)
#pragma unroll
    for (int j = 0; j < 8; ++j) a2[kk][j] = (bf16)(acc[kk][j] * inv);

  int rb = n0 + (g << 2);
#pragma unroll
  for (int j = 0; j < 8; ++j) {
    int row = j * 16 + lr;
    int rbase = row * 256 + g * 64;         // permuted-k B-fragment base
    f32x4 cs = {0.f, 0.f, 0.f, 0.f};
    f32x4 cn = {0.f, 0.f, 0.f, 0.f};
#pragma unroll
    for (int kk = 0; kk < 4; ++kk) {
      int ro = swz(rbase + kk * 16);        // elements g*32 + kk*8 + [0,8)
      bf16x8 bs = *(const bf16x8*)(smem + ro);
      bf16x8 bn = *(const bf16x8*)(smem + 32768 + ro);
      cs = __builtin_amdgcn_mfma_f32_16x16x32_bf16(a1[kk], bs, cs, 0, 0, 0);
      cn = __builtin_amdgcn_mfma_f32_16x16x32_bf16(a2[kk], bn, cn, 0, 0, 0);
    }
    int col = j * 16 + lr;
    float bb = bias[col];
#pragma unroll
    for (int r = 0; r < 4; ++r) {
      size_t idx = (size_t)(rb + r) * DD + col;
      float v = cs[r] + cn[r] + bb;
      if (MODE == 0) H1out[idx] = (bf16)v;
      else           Resb[idx] = (bf16)(Xres[idx] + (float)Hb[idx] + 0.5f * v);
    }
  }
}

// ---- fused attention scores, LDS-staged W_attn --------------------------
__global__ __launch_bounds__(512, 4) void k_attn2(const bf16* __restrict__ resb,
                                                  const float* __restrict__ v2f,
                                                  const bf16* __restrict__ Wab,
                                                  const float* __restrict__ bias,
                                                  const float* __restrict__ att,
                                                  float* __restrict__ partial,
                                                  int nbA, int N) {
  __shared__ char smem[32768];   // [128 rows][256 B], swizzled
  __shared__ float smr[8];
  int t = threadIdx.x;
#pragma unroll
  for (int it = 0; it < 4; ++it) {
    int o = (it * 512 + t) * 16;            // linear byte offset in matrix
    *(bf16x8*)(smem + swz(o)) = *(const bf16x8*)(Wab + o / 2);
  }
  __syncthreads();

  int wv = t >> 6;
  int lane = t & 63;
  int gwid = blockIdx.x * 8 + wv;
  int view = gwid & 1;
  int tile = gwid >> 1;
  int n0 = tile << 4;
  float part = 0.f;
  if (n0 < N) {
    int lr = lane & 15;
    int lk = (lane >> 4) << 3;
    bf16x8 a[4];
    if (view) {
      const float* ap = v2f + (size_t)(n0 + lr) * DD + lk;
#pragma unroll
      for (int kk = 0; kk < 4; ++kk) a[kk] = cvt8(ap + kk * 32);
    } else {
      const bf16* ap = resb + (size_t)(n0 + lr) * DD + lk;
#pragma unroll
      for (int kk = 0; kk < 4; ++kk) a[kk] = *(const bf16x8*)(ap + kk * 32);
    }
#pragma unroll
    for (int j = 0; j < 8; ++j) {
      int row = j * 16 + lr;
      int rbase = row * 256 + lk * 2;
      f32x4 c = {0.f, 0.f, 0.f, 0.f};
#pragma unroll
      for (int kk = 0; kk < 4; ++kk) {
        bf16x8 bw = *(const bf16x8*)(smem + swz(rbase + kk * 64));
        c = __builtin_amdgcn_mfma_f32_16x16x32_bf16(a[kk], bw, c, 0, 0, 0);
      }
      int col = j * 16 + lr;
      float aw = att[col], bb = bias[col];
#pragma unroll
      for (int r = 0; r < 4; ++r) part += aw * ftanh(c[r] + bb);
    }
  }
#pragma unroll
  for (int d = 1; d < 64; d <<= 1) part += __shfl_xor(part, d);
  if (lane == 0) smr[wv] = part;
  __syncthreads();
  if (t == 0) {
    partial[blockIdx.x]       = smr[0] + smr[2] + smr[4] + smr[6];  // view 0
    partial[nbA + blockIdx.x] = smr[1] + smr[3] + smr[5] + smr[7];  // view 1
  }
}

// ---- reduce partials -> scores[2] ---------------------------------------
__global__ __launch_bounds__(256) void k_score(const float* __restrict__ partial,
                                               float* __restrict__ scores, int nbA) {
  __shared__ float sm[256];
  int t = threadIdx.x;
#pragma unroll
  for (int v = 0; v < 2; ++v) {
    float s = 0.f;
    for (int i = t; i < nbA; i += 256) s += partial[v * nbA + i];
    sm[t] = s;
    __syncthreads();
#pragma unroll
    for (int d = 128; d > 0; d >>= 1) {
      if (t < d) sm[t] += sm[t + d];
      __syncthreads();
    }
    if (t == 0) scores[v] = sm[0];
    __syncthreads();
  }
}

// ---- final blend: out = b0*res(bf16) + b1*view2(f32) --------------------
__global__ void k_fin(float* __restrict__ out, const bf16* __restrict__ resb,
                      const float* __restrict__ v2,
                      const float* __restrict__ scores, float invN, int total8) {
  int i = blockIdx.x * 256 + threadIdx.x;
  if (i >= total8) return;
  float s0 = scores[0] * invN, s1 = scores[1] * invN;
  float m = fmaxf(s0, s1);
  float e0 = expf(s0 - m), e1 = expf(s1 - m);
  float inv = 1.0f / (e0 + e1);
  float b0 = e0 * inv, b1 = e1 * inv;
  bf16x8 r = ((const bf16x8*)resb)[i];
  f32x4 w0 = ((const f32x4*)v2)[2 * i];
  f32x4 w1 = ((const f32x4*)v2)[2 * i + 1];
  f32x4 o0, o1;
#pragma unroll
  for (int j = 0; j < 4; ++j) {
    o0[j] = b0 * (float)r[j] + b1 * w0[j];
    o1[j] = b0 * (float)r[4 + j] + b1 * w1[j];
  }
  ((f32x4*)out)[2 * i] = o0;
  ((f32x4*)out)[2 * i + 1] = o1;
}

extern "C" void kernel_launch(void* const* d_in, const int* in_sizes, int n_in,
                              void* d_out, int out_size, void* d_ws, size_t ws_size,
                              hipStream_t stream) {
  const float* x   = (const float*)d_in[0];
  const float* v2  = (const float*)d_in[1];
  const float* Wn1 = (const float*)d_in[2];
  const float* Ws1 = (const float*)d_in[3];
  const float* b1  = (const float*)d_in[4];
  const float* Wn2 = (const float*)d_in[5];
  const float* Ws2 = (const float*)d_in[6];
  const float* b2  = (const float*)d_in[7];
  const float* Wa  = (const float*)d_in[8];
  const float* ba  = (const float*)d_in[9];
  const float* att = (const float*)d_in[10];
  const int*  src  = (const int*)d_in[11];
  const int*  dst  = (const int*)d_in[12];
  const int D = in_sizes[4];        // 128
  const int N = in_sizes[0] / D;    // 50000
  const int E = in_sizes[11];       // 640000
  float* out = (float*)d_out;

  char* ws = (char*)d_ws;
  size_t o = 0;
  auto alloc = [&](size_t bytes) -> void* {
    void* p = ws + o;
    o += (bytes + 255) & ~(size_t)255;
    return p;
  };
  int*  cnt    = (int*)alloc((size_t)N * 4);
  int*  offs   = (int*)alloc((size_t)(N + 1) * 4);
  int*  cursor = (int*)alloc((size_t)N * 4);
  int*  ssrc   = (int*)alloc((size_t)E * 4);
  bf16* xb     = (bf16*)alloc((size_t)N * D * 2);
  bf16* h1b    = (bf16*)alloc((size_t)N * D * 2);
  bf16* resb   = (bf16*)alloc((size_t)N * D * 2);
  unsigned char* xb8  = (unsigned char*)alloc((size_t)N * D);
  unsigned char* h1b8 = (unsigned char*)alloc((size_t)N * D);
  bf16* wb     = (bf16*)alloc((size_t)5 * D * D * 2);
  float* sc    = (float*)alloc(2 * 4);
  int nb = (N + 255) / 256;
  int*  bsum   = (int*)alloc((size_t)nb * 4);

  int tilesPerView = (N + 15) / 16;          // 3125
  int attnWaves = 2 * tilesPerView;          // 6250
  int nbA = (attnWaves + 7) / 8;             // 782 blocks (8 waves each)
  float* apart = (float*)alloc((size_t)2 * nbA * 4);

  // fused prologue
  int nbZ = (N + 255) / 256;                 // zero cnt
  int nbW = (5 * D * D + 255) / 256;         // weights -> bf16
  int nbX = (N * D / 8 + 255) / 256;         // x -> bf16 + fp8
  k_prep<<<nbZ + nbW + nbX, 256, 0, stream>>>(cnt, N, Ws1, Wn1, Ws2, Wn2, Wa, wb,
                                              5 * D * D, x, xb, xb8, N * D / 8,
                                              nbZ, nbW);

  k_hist<<<(E + 255) / 256, 256, 0, stream>>>(dst, cnt, E);
  k_scan1<<<nb, 256, 0, stream>>>(cnt, bsum, N);
  k_scan2<<<1, 256, 0, stream>>>(bsum, nb);
  k_scan3<<<nb, 256, 0, stream>>>(cnt, bsum, offs, cursor, N);
  k_scatter<<<(E + 255) / 256, 256, 0, stream>>>(src, dst, cursor, ssrc, E);

  int layerBlocks = 256;                     // 1 block/CU; waves CU-spread

  // layer 1: h1 (bf16) = x@Ws1^T + mean_nb(x,fp8)@Wn1^T + b1
  k_layer<0><<<layerBlocks, 1024, 0, stream>>>(xb, xb8, offs, ssrc, wb, wb + D * D,
                                               b1, nullptr, h1b, nullptr, N);
  // h1 -> fp8 for layer-2 gather
  k_cvt8<<<(N * D / 8 + 255) / 256, 256, 0, stream>>>(h1b, h1b8, N * D / 8);
  // layer 2: res (bf16) = x + h1 + 0.5*h2
  k_layer<1><<<layerBlocks, 1024, 0, stream>>>(h1b, h1b8, offs, ssrc, wb + 2 * D * D,
                                               wb + 3 * D * D, b2, x, nullptr, resb, N);
  // fused attention scores over [res, view2], W_attn LDS-staged
  k_attn2<<<nbA, 512, 0, stream>>>(resb, v2, wb + 4 * D * D, ba, att, apart, nbA, N);
  k_score<<<1, 256, 0, stream>>>(apart, sc, nbA);
  // final blend
  k_fin<<<((N * D / 8) + 255) / 256, 256, 0, stream>>>(out, resb, v2, sc,
                                                       1.0f / (float)N, N * D / 8);
}

// Round 19
// 166.909 us; speedup vs baseline: 1.1085x; 1.0217x over previous
//
#include <hip/hip_runtime.h>

#define DD 128

using bf16 = __bf16;
typedef __bf16 bf16x8 __attribute__((ext_vector_type(8)));
typedef float f32x4 __attribute__((ext_vector_type(4)));
typedef float f32x2 __attribute__((ext_vector_type(2)));

__device__ inline bf16x8 cvt8(const float* p) {
  f32x4 v0 = *(const f32x4*)p;
  f32x4 v1 = *(const f32x4*)(p + 4);
  bf16x8 r;
  r[0] = (bf16)v0[0]; r[1] = (bf16)v0[1]; r[2] = (bf16)v0[2]; r[3] = (bf16)v0[3];
  r[4] = (bf16)v1[0]; r[5] = (bf16)v1[1]; r[6] = (bf16)v1[2]; r[7] = (bf16)v1[3];
  return r;
}

// pack 8 f32 -> 8 fp8 e4m3 (uint2)
__device__ inline uint2 pk8fp8(const float* f) {
  int u0 = __builtin_amdgcn_cvt_pk_fp8_f32(f[0], f[1], 0, 0);
  u0 = __builtin_amdgcn_cvt_pk_fp8_f32(f[2], f[3], u0, 1);
  int u1 = __builtin_amdgcn_cvt_pk_fp8_f32(f[4], f[5], 0, 0);
  u1 = __builtin_amdgcn_cvt_pk_fp8_f32(f[6], f[7], u1, 1);
  uint2 r; r.x = (unsigned)u0; r.y = (unsigned)u1; return r;
}

// unpack one dword (4 fp8) into 4 accumulators
__device__ inline void acc4fp8(unsigned w, float* a) {
  f32x2 p;
  p = __builtin_amdgcn_cvt_pk_f32_fp8(w, 0); a[0] += p.x; a[1] += p.y;
  p = __builtin_amdgcn_cvt_pk_f32_fp8(w, 1); a[2] += p.x; a[3] += p.y;
}

// fast tanh: 1 - 2/(e^{2x}+1); v_exp + v_rcp, saturates correctly at +-1
__device__ inline float ftanh(float x) {
  float e2 = __expf(2.0f * x);
  return 1.0f - 2.0f * __builtin_amdgcn_rcpf(e2 + 1.0f);
}

// XOR swizzle for [128 rows][256 B] LDS tiles (G4)
__device__ inline int swz(int o) { return o ^ (((o >> 8) & 7) << 4); }

// ---- fused prologue: zero cnt | weights->bf16 | x->bf16+fp8 --------------
__global__ void k_prep(int* __restrict__ cnt, int N,
                       const float* __restrict__ w0, const float* __restrict__ w1,
                       const float* __restrict__ w2, const float* __restrict__ w3,
                       const float* __restrict__ w4, bf16* __restrict__ wb, int totalW,
                       const float* __restrict__ x, bf16* __restrict__ xb,
                       unsigned char* __restrict__ xb8, int total8,
                       int nbZ, int nbW) {
  int b = blockIdx.x;
  if (b < nbZ) {
    int i = b * 256 + threadIdx.x;
    if (i < N) cnt[i] = 0;
  } else if (b < nbZ + nbW) {
    int i = (b - nbZ) * 256 + threadIdx.x;
    if (i < totalW) {
      int m = i >> 14;           // DD*DD = 16384
      int r = i & 16383;
      const float* s = m == 0 ? w0 : m == 1 ? w1 : m == 2 ? w2 : m == 3 ? w3 : w4;
      wb[i] = (bf16)s[r];
    }
  } else {
    int i = (b - nbZ - nbW) * 256 + threadIdx.x;
    if (i < total8) {
      float f[8];
      f32x4 v0 = *(const f32x4*)(x + (size_t)i * 8);
      f32x4 v1 = *(const f32x4*)(x + (size_t)i * 8 + 4);
#pragma unroll
      for (int j = 0; j < 4; ++j) { f[j] = v0[j]; f[4 + j] = v1[j]; }
      bf16x8 r;
#pragma unroll
      for (int j = 0; j < 8; ++j) r[j] = (bf16)f[j];
      *(bf16x8*)(xb + (size_t)i * 8) = r;
      *(uint2*)(xb8 + (size_t)i * 8) = pk8fp8(f);
    }
  }
}

// ---- h1 bf16 -> fp8 copy (for layer-2 gather) ---------------------------
__global__ void k_cvt8(const bf16* __restrict__ h, unsigned char* __restrict__ h8,
                       int total8) {
  int i = blockIdx.x * 256 + threadIdx.x;
  if (i >= total8) return;
  bf16x8 v = *(const bf16x8*)(h + (size_t)i * 8);
  float f[8];
#pragma unroll
  for (int j = 0; j < 8; ++j) f[j] = (float)v[j];
  *(uint2*)(h8 + (size_t)i * 8) = pk8fp8(f);
}

// ---- CSR build, XCD-partitioned ------------------------------------------
// Blocks round-robin over the 8 XCDs, so partition p = blockIdx&7 keeps all
// writes for dst in [p*N/8,(p+1)*N/8) on ONE XCD's L2 -> dirty lines are not
// shared across the 8 non-coherent L2s (38 MB of partial-line writebacks in
// the unpartitioned version). dst[] is scanned 8x (L2-cached, cheap).
__global__ void k_hist(const int* __restrict__ dst, int* __restrict__ cnt,
                       int E, int N) {
  int p = blockIdx.x & 7;
  int slice = blockIdx.x >> 3;
  int nslice = gridDim.x >> 3;
  int lo = p * (N >> 3);
  int hi = (p == 7) ? N : lo + (N >> 3);
  for (int e = slice * 256 + threadIdx.x; e < E; e += nslice * 256) {
    int d = dst[e];
    if (d >= lo && d < hi) atomicAdd(&cnt[d], 1);
  }
}

__global__ void k_scatter(const int* __restrict__ src, const int* __restrict__ dst,
                          int* __restrict__ cursor, int* __restrict__ ssrc,
                          int E, int N) {
  int p = blockIdx.x & 7;
  int slice = blockIdx.x >> 3;
  int nslice = gridDim.x >> 3;
  int lo = p * (N >> 3);
  int hi = (p == 7) ? N : lo + (N >> 3);
  for (int e = slice * 256 + threadIdx.x; e < E; e += nslice * 256) {
    int d = dst[e];
    if (d >= lo && d < hi) {
      int pos = atomicAdd(&cursor[d], 1);
      ssrc[pos] = src[e];
    }
  }
}

__global__ __launch_bounds__(256) void k_scan1(const int* __restrict__ cnt,
                                               int* __restrict__ bsum, int N) {
  __shared__ int sm[256];
  int t = threadIdx.x;
  int i = blockIdx.x * 256 + t;
  sm[t] = (i < N) ? cnt[i] : 0;
  __syncthreads();
#pragma unroll
  for (int d = 128; d > 0; d >>= 1) {
    if (t < d) sm[t] += sm[t + d];
    __syncthreads();
  }
  if (t == 0) bsum[blockIdx.x] = sm[0];
}

__global__ __launch_bounds__(256) void k_scan2(int* __restrict__ bsum, int nb) {
  __shared__ int sm[256];
  int t = threadIdx.x;
  int v = (t < nb) ? bsum[t] : 0;
  sm[t] = v;
  __syncthreads();
#pragma unroll
  for (int d = 1; d < 256; d <<= 1) {
    int u = (t >= d) ? sm[t - d] : 0;
    __syncthreads();
    sm[t] += u;
    __syncthreads();
  }
  if (t < nb) bsum[t] = sm[t] - v;   // exclusive prefix
}

__global__ __launch_bounds__(256) void k_scan3(const int* __restrict__ cnt,
                                               const int* __restrict__ bsum,
                                               int* __restrict__ offs,
                                               int* __restrict__ cursor, int N) {
  __shared__ int sm[256];
  int t = threadIdx.x;
  int i = blockIdx.x * 256 + t;
  int v = (i < N) ? cnt[i] : 0;
  sm[t] = v;
  __syncthreads();
#pragma unroll
  for (int d = 1; d < 256; d <<= 1) {
    int u = (t >= d) ? sm[t - d] : 0;
    __syncthreads();
    sm[t] += u;
    __syncthreads();
  }
  int incl = sm[t];
  int base = bsum[blockIdx.x];
  if (i < N) {
    int ex = base + incl - v;
    offs[i] = ex;
    cursor[i] = ex;
    if (i == N - 1) offs[N] = base + incl;
  }
}

// ---- fused SAGE layer: aggregate (fp8 gather, K-permuted) + GEMM --------
// Block = 1024 threads (16 waves), Ws+Wn staged in 64 KB swizzled LDS.
// Grid = 256 blocks; tile = wv*gridDim + blockIdx (CU-spread).
// K-PERMUTED GEMM: lane-group g / MFMA step kk carries global
// k = g*32 + kk*8 + j (A and B agree) -> per-edge gather footprint is
// CONTIGUOUS 32 fp8 bytes = 2 dwordx4 requests/edge.
// MODE 0: H1out = (bf16)v
// MODE 1: Resb = (bf16)(Xres + h1 + 0.5*v)
template <int MODE>
__global__ __launch_bounds__(1024, 1) void k_layer(const bf16* __restrict__ Hb,
                                                   const unsigned char* __restrict__ Hb8,
                                                   const int* __restrict__ offs,
                                                   const int* __restrict__ ssrc,
                                                   const bf16* __restrict__ Wsb,
                                                   const bf16* __restrict__ Wnb,
                                                   const float* __restrict__ bias,
                                                   const float* __restrict__ Xres,
                                                   bf16* __restrict__ H1out,
                                                   bf16* __restrict__ Resb, int N) {
  __shared__ char smem[65536];   // [2][128 rows][256 B], swizzled
  int t = threadIdx.x;
#pragma unroll
  for (int m = 0; m < 2; ++m) {
    const bf16* wsrc = m ? Wnb : Wsb;
#pragma unroll
    for (int it = 0; it < 2; ++it) {
      int o = (it * 1024 + t) * 16;         // linear byte offset in matrix
      *(bf16x8*)(smem + m * 32768 + swz(o)) = *(const bf16x8*)(wsrc + o / 2);
    }
  }
  __syncthreads();

  int wv = t >> 6;
  int lane = t & 63;
  int tile = wv * gridDim.x + blockIdx.x;   // CU-spread tile mapping
  int n0 = tile << 4;
  if (n0 >= N) return;
  int lr = lane & 15;
  int g = lane >> 4;

  int node = n0 + lr;

  // A1 (self) fragments, permuted k: a1[kk] = elements g*32 + kk*8 + [0,8)
  const bf16* a1p = Hb + (size_t)node * DD + g * 32;
  bf16x8 a1[4];
#pragma unroll
  for (int kk = 0; kk < 4; ++kk) a1[kk] = *(const bf16x8*)(a1p + kk * 8);

  // aggregate neighbor mean: contiguous 32 fp8 bytes/lane = 2 requests/edge
  int beg = offs[node], end = offs[node + 1];
  float acc[4][8];
#pragma unroll
  for (int kk = 0; kk < 4; ++kk)
#pragma unroll
    for (int j = 0; j < 8; ++j) acc[kk][j] = 0.f;
  for (int i = beg; i < end; ++i) {
    int s = ssrc[i];
    const unsigned char* hp = Hb8 + (size_t)s * DD + g * 32;
    uint4 u0 = *(const uint4*)(hp);         // elements g*32 + [0,16)
    uint4 u1 = *(const uint4*)(hp + 16);    // elements g*32 + [16,32)
    acc4fp8(u0.x, &acc[0][0]); acc4fp8(u0.y, &acc[0][4]);
    acc4fp8(u0.z, &acc[1][0]); acc4fp8(u0.w, &acc[1][4]);
    acc4fp8(u1.x, &acc[2][0]); acc4fp8(u1.y, &acc[2][4]);
    acc4fp8(u1.z, &acc[3][0]); acc4fp8(u1.w, &acc[3][4]);
  }
  float inv = (end > beg) ? 1.0f / (float)(end - beg) : 0.f;
  bf16x8 a2[4];
#pragma unroll
  for (int kk = 0; kk < 4; ++kk)
#pragma unroll
    for (int j = 0; j < 8; ++j) a2[kk][j] = (bf16)(acc[kk][j] * inv);

  int rb = n0 + (g << 2);
#pragma unroll
  for (int j = 0; j < 8; ++j) {
    int row = j * 16 + lr;
    int rbase = row * 256 + g * 64;         // permuted-k B-fragment base
    f32x4 cs = {0.f, 0.f, 0.f, 0.f};
    f32x4 cn = {0.f, 0.f, 0.f, 0.f};
#pragma unroll
    for (int kk = 0; kk < 4; ++kk) {
      int ro = swz(rbase + kk * 16);        // elements g*32 + kk*8 + [0,8)
      bf16x8 bs = *(const bf16x8*)(smem + ro);
      bf16x8 bn = *(const bf16x8*)(smem + 32768 + ro);
      cs = __builtin_amdgcn_mfma_f32_16x16x32_bf16(a1[kk], bs, cs, 0, 0, 0);
      cn = __builtin_amdgcn_mfma_f32_16x16x32_bf16(a2[kk], bn, cn, 0, 0, 0);
    }
    int col = j * 16 + lr;
    float bb = bias[col];
#pragma unroll
    for (int r = 0; r < 4; ++r) {
      size_t idx = (size_t)(rb + r) * DD + col;
      float v = cs[r] + cn[r] + bb;
      if (MODE == 0) H1out[idx] = (bf16)v;
      else           Resb[idx] = (bf16)(Xres[idx] + (float)Hb[idx] + 0.5f * v);
    }
  }
}

// ---- fused attention scores, LDS-staged W_attn --------------------------
__global__ __launch_bounds__(512, 4) void k_attn2(const bf16* __restrict__ resb,
                                                  const float* __restrict__ v2f,
                                                  const bf16* __restrict__ Wab,
                                                  const float* __restrict__ bias,
                                                  const float* __restrict__ att,
                                                  float* __restrict__ partial,
                                                  int nbA, int N) {
  __shared__ char smem[32768];   // [128 rows][256 B], swizzled
  __shared__ float smr[8];
  int t = threadIdx.x;
#pragma unroll
  for (int it = 0; it < 4; ++it) {
    int o = (it * 512 + t) * 16;            // linear byte offset in matrix
    *(bf16x8*)(smem + swz(o)) = *(const bf16x8*)(Wab + o / 2);
  }
  __syncthreads();

  int wv = t >> 6;
  int lane = t & 63;
  int gwid = blockIdx.x * 8 + wv;
  int view = gwid & 1;
  int tile = gwid >> 1;
  int n0 = tile << 4;
  float part = 0.f;
  if (n0 < N) {
    int lr = lane & 15;
    int lk = (lane >> 4) << 3;
    bf16x8 a[4];
    if (view) {
      const float* ap = v2f + (size_t)(n0 + lr) * DD + lk;
#pragma unroll
      for (int kk = 0; kk < 4; ++kk) a[kk] = cvt8(ap + kk * 32);
    } else {
      const bf16* ap = resb + (size_t)(n0 + lr) * DD + lk;
#pragma unroll
      for (int kk = 0; kk < 4; ++kk) a[kk] = *(const bf16x8*)(ap + kk * 32);
    }
#pragma unroll
    for (int j = 0; j < 8; ++j) {
      int row = j * 16 + lr;
      int rbase = row * 256 + lk * 2;
      f32x4 c = {0.f, 0.f, 0.f, 0.f};
#pragma unroll
      for (int kk = 0; kk < 4; ++kk) {
        bf16x8 bw = *(const bf16x8*)(smem + swz(rbase + kk * 64));
        c = __builtin_amdgcn_mfma_f32_16x16x32_bf16(a[kk], bw, c, 0, 0, 0);
      }
      int col = j * 16 + lr;
      float aw = att[col], bb = bias[col];
#pragma unroll
      for (int r = 0; r < 4; ++r) part += aw * ftanh(c[r] + bb);
    }
  }
#pragma unroll
  for (int d = 1; d < 64; d <<= 1) part += __shfl_xor(part, d);
  if (lane == 0) smr[wv] = part;
  __syncthreads();
  if (t == 0) {
    partial[blockIdx.x]       = smr[0] + smr[2] + smr[4] + smr[6];  // view 0
    partial[nbA + blockIdx.x] = smr[1] + smr[3] + smr[5] + smr[7];  // view 1
  }
}

// ---- reduce partials -> scores[2] ---------------------------------------
__global__ __launch_bounds__(256) void k_score(const float* __restrict__ partial,
                                               float* __restrict__ scores, int nbA) {
  __shared__ float sm[256];
  int t = threadIdx.x;
#pragma unroll
  for (int v = 0; v < 2; ++v) {
    float s = 0.f;
    for (int i = t; i < nbA; i += 256) s += partial[v * nbA + i];
    sm[t] = s;
    __syncthreads();
#pragma unroll
    for (int d = 128; d > 0; d >>= 1) {
      if (t < d) sm[t] += sm[t + d];
      __syncthreads();
    }
    if (t == 0) scores[v] = sm[0];
    __syncthreads();
  }
}

// ---- final blend: out = b0*res(bf16) + b1*view2(f32) --------------------
__global__ void k_fin(float* __restrict__ out, const bf16* __restrict__ resb,
                      const float* __restrict__ v2,
                      const float* __restrict__ scores, float invN, int total8) {
  int i = blockIdx.x * 256 + threadIdx.x;
  if (i >= total8) return;
  float s0 = scores[0] * invN, s1 = scores[1] * invN;
  float m = fmaxf(s0, s1);
  float e0 = expf(s0 - m), e1 = expf(s1 - m);
  float inv = 1.0f / (e0 + e1);
  float b0 = e0 * inv, b1 = e1 * inv;
  bf16x8 r = ((const bf16x8*)resb)[i];
  f32x4 w0 = ((const f32x4*)v2)[2 * i];
  f32x4 w1 = ((const f32x4*)v2)[2 * i + 1];
  f32x4 o0, o1;
#pragma unroll
  for (int j = 0; j < 4; ++j) {
    o0[j] = b0 * (float)r[j] + b1 * w0[j];
    o1[j] = b0 * (float)r[4 + j] + b1 * w1[j];
  }
  ((f32x4*)out)[2 * i] = o0;
  ((f32x4*)out)[2 * i + 1] = o1;
}

extern "C" void kernel_launch(void* const* d_in, const int* in_sizes, int n_in,
                              void* d_out, int out_size, void* d_ws, size_t ws_size,
                              hipStream_t stream) {
  const float* x   = (const float*)d_in[0];
  const float* v2  = (const float*)d_in[1];
  const float* Wn1 = (const float*)d_in[2];
  const float* Ws1 = (const float*)d_in[3];
  const float* b1  = (const float*)d_in[4];
  const float* Wn2 = (const float*)d_in[5];
  const float* Ws2 = (const float*)d_in[6];
  const float* b2  = (const float*)d_in[7];
  const float* Wa  = (const float*)d_in[8];
  const float* ba  = (const float*)d_in[9];
  const float* att = (const float*)d_in[10];
  const int*  src  = (const int*)d_in[11];
  const int*  dst  = (const int*)d_in[12];
  const int D = in_sizes[4];        // 128
  const int N = in_sizes[0] / D;    // 50000
  const int E = in_sizes[11];       // 640000
  float* out = (float*)d_out;

  char* ws = (char*)d_ws;
  size_t o = 0;
  auto alloc = [&](size_t bytes) -> void* {
    void* p = ws + o;
    o += (bytes + 255) & ~(size_t)255;
    return p;
  };
  int*  cnt    = (int*)alloc((size_t)N * 4);
  int*  offs   = (int*)alloc((size_t)(N + 1) * 4);
  int*  cursor = (int*)alloc((size_t)N * 4);
  int*  ssrc   = (int*)alloc((size_t)E * 4);
  bf16* xb     = (bf16*)alloc((size_t)N * D * 2);
  bf16* h1b    = (bf16*)alloc((size_t)N * D * 2);
  bf16* resb   = (bf16*)alloc((size_t)N * D * 2);
  unsigned char* xb8  = (unsigned char*)alloc((size_t)N * D);
  unsigned char* h1b8 = (unsigned char*)alloc((size_t)N * D);
  bf16* wb     = (bf16*)alloc((size_t)5 * D * D * 2);
  float* sc    = (float*)alloc(2 * 4);
  int nb = (N + 255) / 256;
  int*  bsum   = (int*)alloc((size_t)nb * 4);

  int tilesPerView = (N + 15) / 16;          // 3125
  int attnWaves = 2 * tilesPerView;          // 6250
  int nbA = (attnWaves + 7) / 8;             // 782 blocks (8 waves each)
  float* apart = (float*)alloc((size_t)2 * nbA * 4);

  // fused prologue
  int nbZ = (N + 255) / 256;                 // zero cnt
  int nbW = (5 * D * D + 255) / 256;         // weights -> bf16
  int nbX = (N * D / 8 + 255) / 256;         // x -> bf16 + fp8
  k_prep<<<nbZ + nbW + nbX, 256, 0, stream>>>(cnt, N, Ws1, Wn1, Ws2, Wn2, Wa, wb,
                                              5 * D * D, x, xb, xb8, N * D / 8,
                                              nbZ, nbW);

  // XCD-partitioned CSR build (2048 blocks: 256 slices x 8 partitions)
  k_hist<<<2048, 256, 0, stream>>>(dst, cnt, E, N);
  k_scan1<<<nb, 256, 0, stream>>>(cnt, bsum, N);
  k_scan2<<<1, 256, 0, stream>>>(bsum, nb);
  k_scan3<<<nb, 256, 0, stream>>>(cnt, bsum, offs, cursor, N);
  k_scatter<<<2048, 256, 0, stream>>>(src, dst, cursor, ssrc, E, N);

  int layerBlocks = 256;                     // 1 block/CU; waves CU-spread

  // layer 1: h1 (bf16) = x@Ws1^T + mean_nb(x,fp8)@Wn1^T + b1
  k_layer<0><<<layerBlocks, 1024, 0, stream>>>(xb, xb8, offs, ssrc, wb, wb + D * D,
                                               b1, nullptr, h1b, nullptr, N);
  // h1 -> fp8 for layer-2 gather
  k_cvt8<<<(N * D / 8 + 255) / 256, 256, 0, stream>>>(h1b, h1b8, N * D / 8);
  // layer 2: res (bf16) = x + h1 + 0.5*h2
  k_layer<1><<<layerBlocks, 1024, 0, stream>>>(h1b, h1b8, offs, ssrc, wb + 2 * D * D,
                                               wb + 3 * D * D, b2, x, nullptr, resb, N);
  // fused attention scores over [res, view2], W_attn LDS-staged
  k_attn2<<<nbA, 512, 0, stream>>>(resb, v2, wb + 4 * D * D, ba, att, apart, nbA, N);
  k_score<<<1, 256, 0, stream>>>(apart, sc, nbA);
  // final blend
  k_fin<<<((N * D / 8) + 255) / 256, 256, 0, stream>>>(out, resb, v2, sc,
                                                       1.0f / (float)N, N * D / 8);
}

// Round 20
// 162.329 us; speedup vs baseline: 1.1398x; 1.0282x over previous
//
#include <hip/hip_runtime.h>

#define DD 128

using bf16 = __bf16;
typedef __bf16 bf16x8 __attribute__((ext_vector_type(8)));
typedef float f32x4 __attribute__((ext_vector_type(4)));
typedef float f32x2 __attribute__((ext_vector_type(2)));

__device__ inline bf16x8 cvt8(const float* p) {
  f32x4 v0 = *(const f32x4*)p;
  f32x4 v1 = *(const f32x4*)(p + 4);
  bf16x8 r;
  r[0] = (bf16)v0[0]; r[1] = (bf16)v0[1]; r[2] = (bf16)v0[2]; r[3] = (bf16)v0[3];
  r[4] = (bf16)v1[0]; r[5] = (bf16)v1[1]; r[6] = (bf16)v1[2]; r[7] = (bf16)v1[3];
  return r;
}

// pack 8 f32 -> 8 fp8 e4m3 (uint2)
__device__ inline uint2 pk8fp8(const float* f) {
  int u0 = __builtin_amdgcn_cvt_pk_fp8_f32(f[0], f[1], 0, 0);
  u0 = __builtin_amdgcn_cvt_pk_fp8_f32(f[2], f[3], u0, 1);
  int u1 = __builtin_amdgcn_cvt_pk_fp8_f32(f[4], f[5], 0, 0);
  u1 = __builtin_amdgcn_cvt_pk_fp8_f32(f[6], f[7], u1, 1);
  uint2 r; r.x = (unsigned)u0; r.y = (unsigned)u1; return r;
}

// unpack one dword (4 fp8) into 4 accumulators
__device__ inline void acc4fp8(unsigned w, float* a) {
  f32x2 p;
  p = __builtin_amdgcn_cvt_pk_f32_fp8(w, 0); a[0] += p.x; a[1] += p.y;
  p = __builtin_amdgcn_cvt_pk_f32_fp8(w, 1); a[2] += p.x; a[3] += p.y;
}

// fast tanh: 1 - 2/(e^{2x}+1); v_exp + v_rcp, saturates correctly at +-1
__device__ inline float ftanh(float x) {
  float e2 = __expf(2.0f * x);
  return 1.0f - 2.0f * __builtin_amdgcn_rcpf(e2 + 1.0f);
}

// XOR swizzle for [128 rows][256 B] LDS tiles (G4)
__device__ inline int swz(int o) { return o ^ (((o >> 8) & 7) << 4); }

// ---- fused prologue: zero cnt | weights->bf16 | x->bf16+fp8 --------------
// Layer-2 weight matrices (m=2,3) are stored with the K dimension permuted
// by sigma(p) = (p&7)*16 + (p>>3) so they match h1's transposed storage
// (h1 stored[p] = h1[sigma(p)]; dot over p == natural dot).
__global__ void k_prep(int* __restrict__ cnt, int N,
                       const float* __restrict__ w0, const float* __restrict__ w1,
                       const float* __restrict__ w2, const float* __restrict__ w3,
                       const float* __restrict__ w4, bf16* __restrict__ wb, int totalW,
                       const float* __restrict__ x, bf16* __restrict__ xb,
                       unsigned char* __restrict__ xb8, int total8,
                       int nbZ, int nbW) {
  int b = blockIdx.x;
  if (b < nbZ) {
    int i = b * 256 + threadIdx.x;
    if (i < N) cnt[i] = 0;
  } else if (b < nbZ + nbW) {
    int i = (b - nbZ) * 256 + threadIdx.x;
    if (i < totalW) {
      int m = i >> 14;           // DD*DD = 16384
      int r = i & 16383;
      const float* s = m == 0 ? w0 : m == 1 ? w1 : m == 2 ? w2 : m == 3 ? w3 : w4;
      int srcIdx = r;
      if (m == 2 || m == 3) {    // permute K-dim for layer-2 matrices
        int row = r >> 7, p = r & 127;
        srcIdx = row * 128 + ((p & 7) * 16 + (p >> 3));
      }
      wb[i] = (bf16)s[srcIdx];
    }
  } else {
    int i = (b - nbZ - nbW) * 256 + threadIdx.x;
    if (i < total8) {
      float f[8];
      f32x4 v0 = *(const f32x4*)(x + (size_t)i * 8);
      f32x4 v1 = *(const f32x4*)(x + (size_t)i * 8 + 4);
#pragma unroll
      for (int j = 0; j < 4; ++j) { f[j] = v0[j]; f[4 + j] = v1[j]; }
      bf16x8 r;
#pragma unroll
      for (int j = 0; j < 8; ++j) r[j] = (bf16)f[j];
      *(bf16x8*)(xb + (size_t)i * 8) = r;
      *(uint2*)(xb8 + (size_t)i * 8) = pk8fp8(f);
    }
  }
}

// ---- CSR build, XCD-partitioned ------------------------------------------
__global__ void k_hist(const int* __restrict__ dst, int* __restrict__ cnt,
                       int E, int N) {
  int p = blockIdx.x & 7;
  int slice = blockIdx.x >> 3;
  int nslice = gridDim.x >> 3;
  int lo = p * (N >> 3);
  int hi = (p == 7) ? N : lo + (N >> 3);
  for (int e = slice * 256 + threadIdx.x; e < E; e += nslice * 256) {
    int d = dst[e];
    if (d >= lo && d < hi) atomicAdd(&cnt[d], 1);
  }
}

__global__ void k_scatter(const int* __restrict__ src, const int* __restrict__ dst,
                          int* __restrict__ cursor, int* __restrict__ ssrc,
                          int E, int N) {
  int p = blockIdx.x & 7;
  int slice = blockIdx.x >> 3;
  int nslice = gridDim.x >> 3;
  int lo = p * (N >> 3);
  int hi = (p == 7) ? N : lo + (N >> 3);
  for (int e = slice * 256 + threadIdx.x; e < E; e += nslice * 256) {
    int d = dst[e];
    if (d >= lo && d < hi) {
      int pos = atomicAdd(&cursor[d], 1);
      ssrc[pos] = src[e];
    }
  }
}

__global__ __launch_bounds__(256) void k_scan1(const int* __restrict__ cnt,
                                               int* __restrict__ bsum, int N) {
  __shared__ int sm[256];
  int t = threadIdx.x;
  int i = blockIdx.x * 256 + t;
  sm[t] = (i < N) ? cnt[i] : 0;
  __syncthreads();
#pragma unroll
  for (int d = 128; d > 0; d >>= 1) {
    if (t < d) sm[t] += sm[t + d];
    __syncthreads();
  }
  if (t == 0) bsum[blockIdx.x] = sm[0];
}

__global__ __launch_bounds__(256) void k_scan2(int* __restrict__ bsum, int nb) {
  __shared__ int sm[256];
  int t = threadIdx.x;
  int v = (t < nb) ? bsum[t] : 0;
  sm[t] = v;
  __syncthreads();
#pragma unroll
  for (int d = 1; d < 256; d <<= 1) {
    int u = (t >= d) ? sm[t - d] : 0;
    __syncthreads();
    sm[t] += u;
    __syncthreads();
  }
  if (t < nb) bsum[t] = sm[t] - v;   // exclusive prefix
}

__global__ __launch_bounds__(256) void k_scan3(const int* __restrict__ cnt,
                                               const int* __restrict__ bsum,
                                               int* __restrict__ offs,
                                               int* __restrict__ cursor, int N) {
  __shared__ int sm[256];
  int t = threadIdx.x;
  int i = blockIdx.x * 256 + t;
  int v = (i < N) ? cnt[i] : 0;
  sm[t] = v;
  __syncthreads();
#pragma unroll
  for (int d = 1; d < 256; d <<= 1) {
    int u = (t >= d) ? sm[t - d] : 0;
    __syncthreads();
    sm[t] += u;
    __syncthreads();
  }
  int incl = sm[t];
  int base = bsum[blockIdx.x];
  if (i < N) {
    int ex = base + incl - v;
    offs[i] = ex;
    cursor[i] = ex;
    if (i == N - 1) offs[N] = base + incl;
  }
}

// ---- fused SAGE layer: aggregate (fp8 gather, K-permuted) + GEMM --------
// Block = 1024 threads (16 waves), Ws+Wn staged in 64 KB swizzled LDS.
// Grid = 256 blocks; tile = wv*gridDim + blockIdx (CU-spread).
// Per-edge gather footprint: CONTIGUOUS 32 fp8 bytes = 2 dwordx4 requests.
// MODE 0: h1 stored TRANSPOSED (stored[p]=h1[sigma(p)], sigma(p)=
//   (p&7)*16+(p>>3)): per (lane,row) one 16B bf16 store + one 8B fp8 store
//   (replaces 32 scalar stores + the separate k_cvt8 kernel). Layer-2's
//   weights are K-permuted in k_prep to match; its A1/gather reads are
//   contiguous in stored order (unchanged code).
// MODE 1: Resb natural = (bf16)(Xres + h1 + 0.5*v); h1 residual read uses
//   the permuted index.
template <int MODE>
__global__ __launch_bounds__(1024, 1) void k_layer(const bf16* __restrict__ Hb,
                                                   const unsigned char* __restrict__ Hb8,
                                                   const int* __restrict__ offs,
                                                   const int* __restrict__ ssrc,
                                                   const bf16* __restrict__ Wsb,
                                                   const bf16* __restrict__ Wnb,
                                                   const float* __restrict__ bias,
                                                   const float* __restrict__ Xres,
                                                   bf16* __restrict__ H1out,
                                                   unsigned char* __restrict__ H1out8,
                                                   bf16* __restrict__ Resb, int N) {
  __shared__ char smem[65536];   // [2][128 rows][256 B], swizzled
  int t = threadIdx.x;
#pragma unroll
  for (int m = 0; m < 2; ++m) {
    const bf16* wsrc = m ? Wnb : Wsb;
#pragma unroll
    for (int it = 0; it < 2; ++it) {
      int o = (it * 1024 + t) * 16;         // linear byte offset in matrix
      *(bf16x8*)(smem + m * 32768 + swz(o)) = *(const bf16x8*)(wsrc + o / 2);
    }
  }
  __syncthreads();

  int wv = t >> 6;
  int lane = t & 63;
  int tile = wv * gridDim.x + blockIdx.x;   // CU-spread tile mapping
  int n0 = tile << 4;
  if (n0 >= N) return;
  int lr = lane & 15;
  int g = lane >> 4;

  int node = n0 + lr;

  // A1 (self) fragments: contiguous in this layer's k-storage order
  const bf16* a1p = Hb + (size_t)node * DD + g * 32;
  bf16x8 a1[4];
#pragma unroll
  for (int kk = 0; kk < 4; ++kk) a1[kk] = *(const bf16x8*)(a1p + kk * 8);

  // aggregate neighbor mean: contiguous 32 fp8 bytes/lane = 2 requests/edge
  int beg = offs[node], end = offs[node + 1];
  float acc[4][8];
#pragma unroll
  for (int kk = 0; kk < 4; ++kk)
#pragma unroll
    for (int j = 0; j < 8; ++j) acc[kk][j] = 0.f;
  for (int i = beg; i < end; ++i) {
    int s = ssrc[i];
    const unsigned char* hp = Hb8 + (size_t)s * DD + g * 32;
    uint4 u0 = *(const uint4*)(hp);
    uint4 u1 = *(const uint4*)(hp + 16);
    acc4fp8(u0.x, &acc[0][0]); acc4fp8(u0.y, &acc[0][4]);
    acc4fp8(u0.z, &acc[1][0]); acc4fp8(u0.w, &acc[1][4]);
    acc4fp8(u1.x, &acc[2][0]); acc4fp8(u1.y, &acc[2][4]);
    acc4fp8(u1.z, &acc[3][0]); acc4fp8(u1.w, &acc[3][4]);
  }
  float inv = (end > beg) ? 1.0f / (float)(end - beg) : 0.f;
  bf16x8 a2[4];
#pragma unroll
  for (int kk = 0; kk < 4; ++kk)
#pragma unroll
    for (int j = 0; j < 8; ++j) a2[kk][j] = (bf16)(acc[kk][j] * inv);

  int rb = n0 + (g << 2);
  f32x4 vreg[8];
#pragma unroll
  for (int j = 0; j < 8; ++j) {
    int row = j * 16 + lr;
    int rbase = row * 256 + g * 64;         // permuted-k B-fragment base
    f32x4 cs = {0.f, 0.f, 0.f, 0.f};
    f32x4 cn = {0.f, 0.f, 0.f, 0.f};
#pragma unroll
    for (int kk = 0; kk < 4; ++kk) {
      int ro = swz(rbase + kk * 16);
      bf16x8 bs = *(const bf16x8*)(smem + ro);
      bf16x8 bn = *(const bf16x8*)(smem + 32768 + ro);
      cs = __builtin_amdgcn_mfma_f32_16x16x32_bf16(a1[kk], bs, cs, 0, 0, 0);
      cn = __builtin_amdgcn_mfma_f32_16x16x32_bf16(a2[kk], bn, cn, 0, 0, 0);
    }
    int col = j * 16 + lr;
    float bb = bias[col];
#pragma unroll
    for (int r = 0; r < 4; ++r) vreg[j][r] = cs[r] + cn[r] + bb;
  }

  if (MODE == 0) {
    // transposed store: col j*16+lr -> stored position lr*8+j
#pragma unroll
    for (int r = 0; r < 4; ++r) {
      float f[8]; bf16x8 hb;
#pragma unroll
      for (int j = 0; j < 8; ++j) { f[j] = vreg[j][r]; hb[j] = (bf16)f[j]; }
      size_t base = (size_t)(rb + r) * DD + lr * 8;
      *(bf16x8*)(H1out + base) = hb;
      *(uint2*)(H1out8 + base) = pk8fp8(f);
    }
  } else {
#pragma unroll
    for (int j = 0; j < 8; ++j) {
      int col = j * 16 + lr;
#pragma unroll
      for (int r = 0; r < 4; ++r) {
        size_t row = (size_t)(rb + r);
        // residual h1 read from transposed storage: pos = (col&15)*8+(col>>4)
        float h1v = (float)Hb[row * DD + lr * 8 + j];
        Resb[row * DD + col] = (bf16)(Xres[row * DD + col] + h1v + 0.5f * vreg[j][r]);
      }
    }
  }
}

// ---- fused attention scores, LDS-staged W_attn --------------------------
__global__ __launch_bounds__(512, 4) void k_attn2(const bf16* __restrict__ resb,
                                                  const float* __restrict__ v2f,
                                                  const bf16* __restrict__ Wab,
                                                  const float* __restrict__ bias,
                                                  const float* __restrict__ att,
                                                  float* __restrict__ partial,
                                                  int nbA, int N) {
  __shared__ char smem[32768];   // [128 rows][256 B], swizzled
  __shared__ float smr[8];
  int t = threadIdx.x;
#pragma unroll
  for (int it = 0; it < 4; ++it) {
    int o = (it * 512 + t) * 16;            // linear byte offset in matrix
    *(bf16x8*)(smem + swz(o)) = *(const bf16x8*)(Wab + o / 2);
  }
  __syncthreads();

  int wv = t >> 6;
  int lane = t & 63;
  int gwid = blockIdx.x * 8 + wv;
  int view = gwid & 1;
  int tile = gwid >> 1;
  int n0 = tile << 4;
  float part = 0.f;
  if (n0 < N) {
    int lr = lane & 15;
    int lk = (lane >> 4) << 3;
    bf16x8 a[4];
    if (view) {
      const float* ap = v2f + (size_t)(n0 + lr) * DD + lk;
#pragma unroll
      for (int kk = 0; kk < 4; ++kk) a[kk] = cvt8(ap + kk * 32);
    } else {
      const bf16* ap = resb + (size_t)(n0 + lr) * DD + lk;
#pragma unroll
      for (int kk = 0; kk < 4; ++kk) a[kk] = *(const bf16x8*)(ap + kk * 32);
    }
#pragma unroll
    for (int j = 0; j < 8; ++j) {
      int row = j * 16 + lr;
      int rbase = row * 256 + lk * 2;
      f32x4 c = {0.f, 0.f, 0.f, 0.f};
#pragma unroll
      for (int kk = 0; kk < 4; ++kk) {
        bf16x8 bw = *(const bf16x8*)(smem + swz(rbase + kk * 64));
        c = __builtin_amdgcn_mfma_f32_16x16x32_bf16(a[kk], bw, c, 0, 0, 0);
      }
      int col = j * 16 + lr;
      float aw = att[col], bb = bias[col];
#pragma unroll
      for (int r = 0; r < 4; ++r) part += aw * ftanh(c[r] + bb);
    }
  }
#pragma unroll
  for (int d = 1; d < 64; d <<= 1) part += __shfl_xor(part, d);
  if (lane == 0) smr[wv] = part;
  __syncthreads();
  if (t == 0) {
    partial[blockIdx.x]       = smr[0] + smr[2] + smr[4] + smr[6];  // view 0
    partial[nbA + blockIdx.x] = smr[1] + smr[3] + smr[5] + smr[7];  // view 1
  }
}

// ---- reduce partials -> scores[2] ---------------------------------------
__global__ __launch_bounds__(256) void k_score(const float* __restrict__ partial,
                                               float* __restrict__ scores, int nbA) {
  __shared__ float sm[256];
  int t = threadIdx.x;
#pragma unroll
  for (int v = 0; v < 2; ++v) {
    float s = 0.f;
    for (int i = t; i < nbA; i += 256) s += partial[v * nbA + i];
    sm[t] = s;
    __syncthreads();
#pragma unroll
    for (int d = 128; d > 0; d >>= 1) {
      if (t < d) sm[t] += sm[t + d];
      __syncthreads();
    }
    if (t == 0) scores[v] = sm[0];
    __syncthreads();
  }
}

// ---- final blend: out = b0*res(bf16) + b1*view2(f32) --------------------
__global__ void k_fin(float* __restrict__ out, const bf16* __restrict__ resb,
                      const float* __restrict__ v2,
                      const float* __restrict__ scores, float invN, int total8) {
  int i = blockIdx.x * 256 + threadIdx.x;
  if (i >= total8) return;
  float s0 = scores[0] * invN, s1 = scores[1] * invN;
  float m = fmaxf(s0, s1);
  float e0 = expf(s0 - m), e1 = expf(s1 - m);
  float inv = 1.0f / (e0 + e1);
  float b0 = e0 * inv, b1 = e1 * inv;
  bf16x8 r = ((const bf16x8*)resb)[i];
  f32x4 w0 = ((const f32x4*)v2)[2 * i];
  f32x4 w1 = ((const f32x4*)v2)[2 * i + 1];
  f32x4 o0, o1;
#pragma unroll
  for (int j = 0; j < 4; ++j) {
    o0[j] = b0 * (float)r[j] + b1 * w0[j];
    o1[j] = b0 * (float)r[4 + j] + b1 * w1[j];
  }
  ((f32x4*)out)[2 * i] = o0;
  ((f32x4*)out)[2 * i + 1] = o1;
}

extern "C" void kernel_launch(void* const* d_in, const int* in_sizes, int n_in,
                              void* d_out, int out_size, void* d_ws, size_t ws_size,
                              hipStream_t stream) {
  const float* x   = (const float*)d_in[0];
  const float* v2  = (const float*)d_in[1];
  const float* Wn1 = (const float*)d_in[2];
  const float* Ws1 = (const float*)d_in[3];
  const float* b1  = (const float*)d_in[4];
  const float* Wn2 = (const float*)d_in[5];
  const float* Ws2 = (const float*)d_in[6];
  const float* b2  = (const float*)d_in[7];
  const float* Wa  = (const float*)d_in[8];
  const float* ba  = (const float*)d_in[9];
  const float* att = (const float*)d_in[10];
  const int*  src  = (const int*)d_in[11];
  const int*  dst  = (const int*)d_in[12];
  const int D = in_sizes[4];        // 128
  const int N = in_sizes[0] / D;    // 50000
  const int E = in_sizes[11];       // 640000
  float* out = (float*)d_out;

  char* ws = (char*)d_ws;
  size_t o = 0;
  auto alloc = [&](size_t bytes) -> void* {
    void* p = ws + o;
    o += (bytes + 255) & ~(size_t)255;
    return p;
  };
  int*  cnt    = (int*)alloc((size_t)N * 4);
  int*  offs   = (int*)alloc((size_t)(N + 1) * 4);
  int*  cursor = (int*)alloc((size_t)N * 4);
  int*  ssrc   = (int*)alloc((size_t)E * 4);
  bf16* xb     = (bf16*)alloc((size_t)N * D * 2);
  bf16* h1b    = (bf16*)alloc((size_t)N * D * 2);
  bf16* resb   = (bf16*)alloc((size_t)N * D * 2);
  unsigned char* xb8  = (unsigned char*)alloc((size_t)N * D);
  unsigned char* h1b8 = (unsigned char*)alloc((size_t)N * D);
  bf16* wb     = (bf16*)alloc((size_t)5 * D * D * 2);
  float* sc    = (float*)alloc(2 * 4);
  int nb = (N + 255) / 256;
  int*  bsum   = (int*)alloc((size_t)nb * 4);

  int tilesPerView = (N + 15) / 16;          // 3125
  int attnWaves = 2 * tilesPerView;          // 6250
  int nbA = (attnWaves + 7) / 8;             // 782 blocks (8 waves each)
  float* apart = (float*)alloc((size_t)2 * nbA * 4);

  // fused prologue
  int nbZ = (N + 255) / 256;                 // zero cnt
  int nbW = (5 * D * D + 255) / 256;         // weights -> bf16 (L2 K-permuted)
  int nbX = (N * D / 8 + 255) / 256;         // x -> bf16 + fp8
  k_prep<<<nbZ + nbW + nbX, 256, 0, stream>>>(cnt, N, Ws1, Wn1, Ws2, Wn2, Wa, wb,
                                              5 * D * D, x, xb, xb8, N * D / 8,
                                              nbZ, nbW);

  // XCD-partitioned CSR build (2048 blocks: 256 slices x 8 partitions)
  k_hist<<<2048, 256, 0, stream>>>(dst, cnt, E, N);
  k_scan1<<<nb, 256, 0, stream>>>(cnt, bsum, N);
  k_scan2<<<1, 256, 0, stream>>>(bsum, nb);
  k_scan3<<<nb, 256, 0, stream>>>(cnt, bsum, offs, cursor, N);
  k_scatter<<<2048, 256, 0, stream>>>(src, dst, cursor, ssrc, E, N);

  int layerBlocks = 256;                     // 1 block/CU; waves CU-spread

  // layer 1: h1 stored transposed (bf16 + fused fp8), no k_cvt8
  k_layer<0><<<layerBlocks, 1024, 0, stream>>>(xb, xb8, offs, ssrc, wb, wb + D * D,
                                               b1, nullptr, h1b, h1b8, nullptr, N);
  // layer 2: res (bf16, natural) = x + h1 + 0.5*h2; K-permuted weights
  k_layer<1><<<layerBlocks, 1024, 0, stream>>>(h1b, h1b8, offs, ssrc, wb + 2 * D * D,
                                               wb + 3 * D * D, b2, x, nullptr, nullptr,
                                               resb, N);
  // fused attention scores over [res, view2], W_attn LDS-staged
  k_attn2<<<nbA, 512, 0, stream>>>(resb, v2, wb + 4 * D * D, ba, att, apart, nbA, N);
  k_score<<<1, 256, 0, stream>>>(apart, sc, nbA);
  // final blend
  k_fin<<<((N * D / 8) + 255) / 256, 256, 0, stream>>>(out, resb, v2, sc,
                                                       1.0f / (float)N, N * D / 8);
}